// Round 1
// baseline (215.663 us; speedup 1.0000x reference)
//
#include <hip/hip_runtime.h>

// SetEq4to4: out[n,so,i,j,k,l] = sum over 69 basis ops (A,B) of
//   sum_d coefs[d,so,idx] * (x summed over complement(A))[broadcast to B] + bias
// n=2, d=8, so=8, N=32, basis=69.
//
// Decomposition:
//   red3[a][n,d,c3]  a=0:(0,1,2)->(i,j,k), 1:(0,1,3)->(i,j,l), 2:(0,2,3)->(i,k,l), 3:(1,2,3)->(j,k,l)
//   red2[b2], red1[b1] derived from red3 (tiny).
//   T2f/T1f = channel-mixed sums over all A of same size.
//   U3[b] = channel-mixed size-3 terms + folded T2f/T1f/bias (each B2/B1 folded into
//           exactly one containing B3):
//     b=0 (0,1,2): + T2(0,1)[p1,p2] T2(0,2)[p1,p3] T2(1,2)[p2,p3] T1(0..2) + bias
//     b=1 (0,1,3): + T2(0,3)[p1,p3] T2(1,3)[p2,p3] T1(3)[p3]
//     b=2 (0,2,3): + T2(2,3)[p2,p3]
//   Final: out = sum_d c[d,so,68]*x + U012[i,j,k] + U013[i,j,l] + U023[i,k,l] + U123[j,k,l]

constexpr size_t R3SZ  = 524288;   // per-a: 16 nd * 32768
constexpr size_t R2SZ  = 16384;    // per-b2: 16 nd * 1024
constexpr size_t R1SZ  = 512;      // per-b1: 16 nd * 32
constexpr size_t R3OFF = 0;
constexpr size_t R2OFF = R3OFF + 4 * R3SZ;   // 2097152
constexpr size_t R1OFF = R2OFF + 6 * R2SZ;   // 2195456
constexpr size_t T2OFF = R1OFF + 4 * R1SZ;   // 2197504
constexpr size_t T1OFF = T2OFF + 6 * R2SZ;   // 2295808
constexpr size_t U3OFF = T1OFF + 4 * R1SZ;   // 2297856
// total ws floats: U3OFF + 4*R3SZ = 4395008  (~17.6 MiB)

// ---------------- Ra: red3 a=0,1,2 (keep i). block = (n*8+d)*32 + i ----------------
__global__ __launch_bounds__(256) void k_red3_keep_i(const float* __restrict__ x,
                                                     float* __restrict__ ws) {
    const int b  = blockIdx.x;          // 0..511
    const int i  = b & 31;
    const int nd = b >> 5;              // n*8+d
    const float* xp = x + ((size_t)nd << 20) + ((size_t)i << 15);
    const int t = threadIdx.x;

    // a=2: r023[i,k,l] = sum_j. thread: k=t>>3, lq=t&7 (coalesced 1KB/wave)
    {
        const int k = t >> 3, lq = t & 7;
        const float* p = xp + k * 32 + lq * 4;
        float4 acc = {0.f, 0.f, 0.f, 0.f};
        #pragma unroll 8
        for (int j = 0; j < 32; ++j) {
            float4 v = *(const float4*)(p + j * 1024);
            acc.x += v.x; acc.y += v.y; acc.z += v.z; acc.w += v.w;
        }
        *(float4*)(ws + R3OFF + 2 * R3SZ + ((size_t)nd << 15) + ((size_t)i << 10)
                   + k * 32 + lq * 4) = acc;
    }
    // a=1: r013[i,j,l] = sum_k. thread: j=t>>3, lq=t&7
    {
        const int j = t >> 3, lq = t & 7;
        const float* p = xp + j * 1024 + lq * 4;
        float4 acc = {0.f, 0.f, 0.f, 0.f};
        #pragma unroll 8
        for (int k = 0; k < 32; ++k) {
            float4 v = *(const float4*)(p + k * 32);
            acc.x += v.x; acc.y += v.y; acc.z += v.z; acc.w += v.w;
        }
        *(float4*)(ws + R3OFF + 1 * R3SZ + ((size_t)nd << 15) + ((size_t)i << 10)
                   + j * 32 + lq * 4) = acc;
    }
    // a=0: r012[i,j,k] = sum_l. shuffle across 8-lane groups (coalesced loads)
    {
        const int g  = t >> 3;          // 0..31
        const int lq = t & 7;
        for (int pass = 0; pass < 32; ++pass) {
            int jk = pass * 32 + g;     // j*32+k
            float4 v = *(const float4*)(xp + jk * 32 + lq * 4);
            float s = v.x + v.y + v.z + v.w;
            s += __shfl_xor(s, 1);
            s += __shfl_xor(s, 2);
            s += __shfl_xor(s, 4);
            if (lq == 0)
                ws[R3OFF + ((size_t)nd << 15) + ((size_t)i << 10) + jk] = s;
        }
    }
}

// ---------------- Rb: red3 a=3 (sum i). block = (n*8+d)*32 + j ----------------
__global__ __launch_bounds__(256) void k_red3_sum_i(const float* __restrict__ x,
                                                    float* __restrict__ ws) {
    const int b  = blockIdx.x;
    const int j  = b & 31;
    const int nd = b >> 5;
    const int t  = threadIdx.x;
    const int k = t >> 3, lq = t & 7;
    const float* p = x + ((size_t)nd << 20) + j * 1024 + k * 32 + lq * 4;
    float4 acc = {0.f, 0.f, 0.f, 0.f};
    #pragma unroll 8
    for (int i = 0; i < 32; ++i) {
        float4 v = *(const float4*)(p + ((size_t)i << 15));
        acc.x += v.x; acc.y += v.y; acc.z += v.z; acc.w += v.w;
    }
    *(float4*)(ws + R3OFF + 3 * R3SZ + ((size_t)nd << 15) + ((size_t)j << 10)
               + k * 32 + lq * 4) = acc;
}

// ---------------- Rc: red2 (6) + red1 (4) from red3 ----------------
__global__ __launch_bounds__(256) void k_red21(float* __restrict__ ws) {
    const int gid = blockIdx.x * 256 + threadIdx.x;   // grid 392*256 = 100352
    if (gid < 98304) {
        const int b2 = gid >> 14;
        const int r  = gid & 16383;
        const int nd = r >> 10;
        const int p = (r >> 5) & 31, q = r & 31;
        const float* r012 = ws + R3OFF + ((size_t)nd << 15);
        const float* r013 = r012 + R3SZ;
        const float* r023 = r012 + 2 * R3SZ;
        float s = 0.f;
        switch (b2) {
            case 0: { const float* s0 = r012 + p * 1024 + q * 32;
                      for (int m = 0; m < 32; ++m) s += s0[m]; } break;
            case 1: { const float* s0 = r012 + p * 1024 + q;
                      for (int m = 0; m < 32; ++m) s += s0[m * 32]; } break;
            case 2: { const float* s0 = r013 + p * 1024 + q;
                      for (int m = 0; m < 32; ++m) s += s0[m * 32]; } break;
            case 3: { const float* s0 = r012 + p * 32 + q;
                      for (int m = 0; m < 32; ++m) s += s0[m * 1024]; } break;
            case 4: { const float* s0 = r013 + p * 32 + q;
                      for (int m = 0; m < 32; ++m) s += s0[m * 1024]; } break;
            default:{ const float* s0 = r023 + p * 32 + q;
                      for (int m = 0; m < 32; ++m) s += s0[m * 1024]; } break;
        }
        ws[R2OFF + (size_t)b2 * R2SZ + (size_t)nd * 1024 + p * 32 + q] = s;
    } else if (gid < 100352) {
        const int e  = gid - 98304;
        const int b1 = e >> 9;
        const int r  = e & 511;
        const int nd = r >> 5, p = r & 31;
        const float* r012 = ws + R3OFF + ((size_t)nd << 15);
        const float* r013 = r012 + R3SZ;
        float s = 0.f;
        if (b1 == 0)      { const float* s0 = r012 + p * 1024;
                            for (int m = 0; m < 1024; ++m) s += s0[m]; }
        else if (b1 == 1) { const float* s0 = r012 + p * 32;
                            for (int a = 0; a < 32; ++a) for (int m = 0; m < 32; ++m)
                                s += s0[a * 1024 + m]; }
        else if (b1 == 2) { const float* s0 = r012 + p;
                            for (int a = 0; a < 32; ++a) for (int m = 0; m < 32; ++m)
                                s += s0[a * 1024 + m * 32]; }
        else              { const float* s0 = r013 + p;
                            for (int a = 0; a < 32; ++a) for (int m = 0; m < 32; ++m)
                                s += s0[a * 1024 + m * 32]; }
        ws[R1OFF + (size_t)b1 * R1SZ + (size_t)nd * 32 + p] = s;
    }
}

// ---------------- M21: T2f/T1f = channel-mixed red2/red1 ----------------
__global__ __launch_bounds__(256) void k_mix21(const float* __restrict__ coefs,
                                               float* __restrict__ ws) {
    __shared__ float cs[4416];
    for (int idx = threadIdx.x; idx < 4416; idx += 256) cs[idx] = coefs[idx];
    __syncthreads();
    const int gid = blockIdx.x * 256 + threadIdx.x;
    if (gid < 98304) {
        const int b2 = gid >> 14;
        const int r  = gid & 16383;
        const int n  = r >> 13;
        const int so = (r >> 10) & 7;
        const int pq = r & 1023;
        float s = 0.f;
        #pragma unroll
        for (int a2 = 0; a2 < 6; ++a2) {
            const float* src = ws + R2OFF + (size_t)a2 * R2SZ + (size_t)(n * 8) * 1024 + pq;
            #pragma unroll
            for (int d = 0; d < 8; ++d)
                s += cs[(d * 8 + so) * 69 + 16 + a2 * 6 + b2] * src[d * 1024];
        }
        ws[T2OFF + (size_t)b2 * R2SZ + (size_t)(n * 8 + so) * 1024 + pq] = s;
    } else if (gid < 100352) {
        const int e  = gid - 98304;
        const int b1 = e >> 9;
        const int r  = e & 511;
        const int n  = r >> 8;
        const int so = (r >> 5) & 7;
        const int p  = r & 31;
        float s = 0.f;
        #pragma unroll
        for (int a1 = 0; a1 < 4; ++a1) {
            const float* src = ws + R1OFF + (size_t)a1 * R1SZ + (size_t)(n * 8) * 32 + p;
            #pragma unroll
            for (int d = 0; d < 8; ++d)
                s += cs[(d * 8 + so) * 69 + a1 * 4 + b1] * src[d * 32];
        }
        ws[T1OFF + (size_t)b1 * R1SZ + (size_t)(n * 8 + so) * 32 + p] = s;
    }
}

// ---------------- M3: U3[b] = mixed red3 + folded T2f/T1f/bias ----------------
__global__ __launch_bounds__(256) void k_mix3(const float* __restrict__ coefs,
                                              const float* __restrict__ bias,
                                              float* __restrict__ ws) {
    __shared__ float cs[4416];
    for (int idx = threadIdx.x; idx < 4416; idx += 256) cs[idx] = coefs[idx];
    __syncthreads();
    const int gid = blockIdx.x * 256 + threadIdx.x;   // 0..65535
    const int n = gid >> 15;
    const int c = gid & 32767;
    const int p1 = c >> 10, p2 = (c >> 5) & 31, p3 = c & 31;
    float v[4][8];
    #pragma unroll
    for (int a = 0; a < 4; ++a)
        #pragma unroll
        for (int d = 0; d < 8; ++d)
            v[a][d] = ws[R3OFF + (size_t)a * R3SZ + (size_t)(n * 8 + d) * 32768 + c];
    const float* T2 = ws + T2OFF;
    const float* T1 = ws + T1OFF;
    #pragma unroll
    for (int b = 0; b < 4; ++b) {
        #pragma unroll
        for (int so = 0; so < 8; ++so) {
            float s = 0.f;
            #pragma unroll
            for (int a = 0; a < 4; ++a)
                #pragma unroll
                for (int d = 0; d < 8; ++d)
                    s += cs[(d * 8 + so) * 69 + 52 + a * 4 + b] * v[a][d];
            const size_t nso = (size_t)(n * 8 + so);
            if (b == 0) {
                s += T2[0 * R2SZ + nso * 1024 + p1 * 32 + p2];
                s += T2[1 * R2SZ + nso * 1024 + p1 * 32 + p3];
                s += T2[3 * R2SZ + nso * 1024 + p2 * 32 + p3];
                s += T1[0 * R1SZ + nso * 32 + p1];
                s += T1[1 * R1SZ + nso * 32 + p2];
                s += T1[2 * R1SZ + nso * 32 + p3];
                s += bias[so];
            } else if (b == 1) {
                s += T2[2 * R2SZ + nso * 1024 + p1 * 32 + p3];
                s += T2[4 * R2SZ + nso * 1024 + p2 * 32 + p3];
                s += T1[3 * R1SZ + nso * 32 + p3];
            } else if (b == 2) {
                s += T2[5 * R2SZ + nso * 1024 + p2 * 32 + p3];
            }
            ws[U3OFF + (size_t)b * R3SZ + nso * 32768 + c] = s;
        }
    }
}

// ---------------- F: final broadcast-add + s=4 channel mix ----------------
__global__ __launch_bounds__(256) void k_final(const float* __restrict__ x,
                                               const float* __restrict__ coefs,
                                               const float* __restrict__ ws,
                                               float* __restrict__ out) {
    __shared__ float c68[64];
    if (threadIdx.x < 64) c68[threadIdx.x] = coefs[threadIdx.x * 69 + 68];
    __syncthreads();
    const int b = blockIdx.x;           // (n*32+i)*32 + j
    const int j = b & 31;
    const int i = (b >> 5) & 31;
    const int n = b >> 10;
    const int t = threadIdx.x;
    const int k = t >> 3, lq = t & 7;

    float4 xv[8];
    const float* xb = x + ((size_t)n << 23) + ((size_t)i << 15) + j * 1024 + k * 32 + lq * 4;
    #pragma unroll
    for (int d = 0; d < 8; ++d) xv[d] = *(const float4*)(xb + ((size_t)d << 20));

    const float* U = ws + U3OFF;
    const size_t c012 = (size_t)i * 1024 + j * 32 + k;
    const size_t c013 = (size_t)i * 1024 + j * 32 + lq * 4;
    const size_t c023 = (size_t)i * 1024 + k * 32 + lq * 4;
    const size_t c123 = (size_t)j * 1024 + k * 32 + lq * 4;

    #pragma unroll
    for (int so = 0; so < 8; ++so) {
        const size_t nso = (size_t)(n * 8 + so) << 15;
        const float  u0 = U[0 * R3SZ + nso + c012];
        const float4 u1 = *(const float4*)(U + 1 * R3SZ + nso + c013);
        const float4 u2 = *(const float4*)(U + 2 * R3SZ + nso + c023);
        const float4 u3 = *(const float4*)(U + 3 * R3SZ + nso + c123);
        float4 acc;
        acc.x = u0 + u1.x + u2.x + u3.x;
        acc.y = u0 + u1.y + u2.y + u3.y;
        acc.z = u0 + u1.z + u2.z + u3.z;
        acc.w = u0 + u1.w + u2.w + u3.w;
        #pragma unroll
        for (int d = 0; d < 8; ++d) {
            const float w = c68[d * 8 + so];
            acc.x += w * xv[d].x; acc.y += w * xv[d].y;
            acc.z += w * xv[d].z; acc.w += w * xv[d].w;
        }
        *(float4*)(out + ((size_t)(n * 8 + so) << 20) + ((size_t)i << 15)
                   + j * 1024 + k * 32 + lq * 4) = acc;
    }
}

extern "C" void kernel_launch(void* const* d_in, const int* in_sizes, int n_in,
                              void* d_out, int out_size, void* d_ws, size_t ws_size,
                              hipStream_t stream) {
    const float* x     = (const float*)d_in[0];
    const float* coefs = (const float*)d_in[1];
    const float* bias  = (const float*)d_in[2];
    float* out = (float*)d_out;
    float* ws  = (float*)d_ws;   // needs ~17.6 MiB

    hipLaunchKernelGGL(k_red3_keep_i, dim3(512),  dim3(256), 0, stream, x, ws);
    hipLaunchKernelGGL(k_red3_sum_i,  dim3(512),  dim3(256), 0, stream, x, ws);
    hipLaunchKernelGGL(k_red21,       dim3(392),  dim3(256), 0, stream, ws);
    hipLaunchKernelGGL(k_mix21,       dim3(392),  dim3(256), 0, stream, coefs, ws);
    hipLaunchKernelGGL(k_mix3,        dim3(256),  dim3(256), 0, stream, coefs, bias, ws);
    hipLaunchKernelGGL(k_final,       dim3(2048), dim3(256), 0, stream, x, coefs, ws, out);
}

// Round 2
// 206.137 us; speedup vs baseline: 1.0462x; 1.0462x over previous
//
#include <hip/hip_runtime.h>

// SetEq4to4: out[n,so,i,j,k,l] = sum over 69 basis ops (A,B) + bias.
// n=2, d=8, so=8, N=32, basis=69.
//
// Pipeline (x read twice + final pass):
//   memset: zero atomic targets (r23, r2, r3)
//   K1 k_r023 (block per (nd,i)):  x -> r023[i,k,l], r02[i,k], r03[i,l], r0[i]
//   K2 k_rowj (block per (nd,j)):  x -> r013[i,j,l], r012[i,j,k], r01[i,j],
//                                       r123[j,k,l] (LDS ds_add over i),
//                                       r12[j,k], r13[j,l], r1[j] (from r123 row),
//                                       r23[k,l] += , r2[k] += , r3[l] += (global atomics)
//   K3 k_mix21: T2f/T1f = channel-mixed red2/red1
//   K4 k_mix3:  U3[b] = mixed red3 + folded T2f/T1f/bias  (so-split for occupancy)
//   K5 k_final: out = sum_d c68*x + U012 + U013 + U023 + U123

constexpr size_t R3SZ  = 524288;   // per-a: 16 nd * 32768
constexpr size_t R2SZ  = 16384;    // per-b2: 16 nd * 1024
constexpr size_t R1SZ  = 512;      // per-b1: 16 nd * 32
constexpr size_t R3OFF = 0;
constexpr size_t R2OFF = R3OFF + 4 * R3SZ;   // red2: b2 0..5 = (01)(02)(03)(12)(13)(23)
constexpr size_t R1OFF = R2OFF + 6 * R2SZ;   // red1: b1 0..3 = (0)(1)(2)(3)
constexpr size_t T2OFF = R1OFF + 4 * R1SZ;
constexpr size_t T1OFF = T2OFF + 6 * R2SZ;
constexpr size_t U3OFF = T1OFF + 4 * R1SZ;
// total ws floats: U3OFF + 4*R3SZ = 4395008  (~17.6 MiB)

// ---------------- K1: r023 + r02 + r03 + r0. block = nd*32 + i ----------------
__global__ __launch_bounds__(1024) void k_r023(const float* __restrict__ x,
                                               float* __restrict__ ws) {
    __shared__ float s03[32];
    const int b  = blockIdx.x;
    const int i  = b & 31;
    const int nd = b >> 5;
    const int t  = threadIdx.x;
    const int k  = t >> 5, jq = (t >> 3) & 3, lq = t & 7;
    if (t < 32) s03[t] = 0.f;
    __syncthreads();

    const float* xp = x + ((size_t)nd << 20) + ((size_t)i << 15)
                        + (size_t)(jq * 8) * 1024 + k * 32 + lq * 4;
    float4 a = {0.f, 0.f, 0.f, 0.f};
    #pragma unroll
    for (int m = 0; m < 8; ++m) {
        float4 v = *(const float4*)(xp + m * 1024);
        a.x += v.x; a.y += v.y; a.z += v.z; a.w += v.w;
    }
    // reduce over jq (lane bits 3,4) -> full j-sum on jq==0 lanes
    a.x += __shfl_xor(a.x, 8);  a.y += __shfl_xor(a.y, 8);
    a.z += __shfl_xor(a.z, 8);  a.w += __shfl_xor(a.w, 8);
    a.x += __shfl_xor(a.x, 16); a.y += __shfl_xor(a.y, 16);
    a.z += __shfl_xor(a.z, 16); a.w += __shfl_xor(a.w, 16);
    // l-sum for r02 (butterfly over lq keeps jq groups separate)
    float rs = a.x + a.y + a.z + a.w;
    rs += __shfl_xor(rs, 1); rs += __shfl_xor(rs, 2); rs += __shfl_xor(rs, 4);
    if (jq == 0) {
        *(float4*)(ws + R3OFF + 2 * R3SZ + ((size_t)nd << 15) + ((size_t)i << 10)
                   + k * 32 + lq * 4) = a;                       // r023[i,k,l]
        atomicAdd(&s03[lq * 4 + 0], a.x);
        atomicAdd(&s03[lq * 4 + 1], a.y);
        atomicAdd(&s03[lq * 4 + 2], a.z);
        atomicAdd(&s03[lq * 4 + 3], a.w);
        if (lq == 0)
            ws[R2OFF + 1 * R2SZ + nd * 1024 + i * 32 + k] = rs;  // r02[i,k]
    }
    __syncthreads();
    if (t < 32) {
        float v = s03[t];
        ws[R2OFF + 2 * R2SZ + nd * 1024 + i * 32 + t] = v;       // r03[i,l]
        v += __shfl_xor(v, 1); v += __shfl_xor(v, 2); v += __shfl_xor(v, 4);
        v += __shfl_xor(v, 8); v += __shfl_xor(v, 16);
        if (t == 0) ws[R1OFF + 0 * R1SZ + nd * 32 + i] = v;      // r0[i]
    }
}

// ---------------- K2: r013/r012/r01 + r123/r12/r13/r1 + atomics r23/r2/r3 ----------------
__global__ __launch_bounds__(1024) void k_rowj(const float* __restrict__ x,
                                               float* __restrict__ ws) {
    __shared__ float s123[1056 + 32];   // s123[33*k + l]; s1 stash at 1056
    const int b  = blockIdx.x;
    const int j  = b & 31;
    const int nd = b >> 5;
    const int t  = threadIdx.x;
    const int i  = t >> 5, kq = (t >> 3) & 3, lq = t & 7;
    for (int q = t; q < 1056; q += 1024) s123[q] = 0.f;
    __syncthreads();

    const float* xp = x + ((size_t)nd << 20) + ((size_t)i << 15)
                        + (size_t)j * 1024 + kq * 256 + lq * 4;
    float4 v[8];
    #pragma unroll
    for (int m = 0; m < 8; ++m) v[m] = *(const float4*)(xp + m * 32);

    // r013[i,j,l] = sum_k: per-thread over 8 k's, then shuffle over kq
    float4 a13 = v[0];
    #pragma unroll
    for (int m = 1; m < 8; ++m) {
        a13.x += v[m].x; a13.y += v[m].y; a13.z += v[m].z; a13.w += v[m].w;
    }
    a13.x += __shfl_xor(a13.x, 8);  a13.y += __shfl_xor(a13.y, 8);
    a13.z += __shfl_xor(a13.z, 8);  a13.w += __shfl_xor(a13.w, 8);
    a13.x += __shfl_xor(a13.x, 16); a13.y += __shfl_xor(a13.y, 16);
    a13.z += __shfl_xor(a13.z, 16); a13.w += __shfl_xor(a13.w, 16);
    if (kq == 0)
        *(float4*)(ws + R3OFF + 1 * R3SZ + ((size_t)nd << 15) + ((size_t)i << 10)
                   + j * 32 + lq * 4) = a13;

    // r012[i,j,k] = sum_l: butterfly over lq per k (all lanes end with full sum)
    float sm[8];
    #pragma unroll
    for (int m = 0; m < 8; ++m) {
        float s = v[m].x + v[m].y + v[m].z + v[m].w;
        s += __shfl_xor(s, 1); s += __shfl_xor(s, 2); s += __shfl_xor(s, 4);
        sm[m] = s;
    }
    if (lq == 0) {
        float4 f0 = {sm[0], sm[1], sm[2], sm[3]};
        float4 f1 = {sm[4], sm[5], sm[6], sm[7]};
        float* dst = ws + R3OFF + ((size_t)nd << 15) + ((size_t)i << 10)
                     + j * 32 + kq * 8;
        *(float4*)(dst) = f0;
        *(float4*)(dst + 4) = f1;
    }
    // r01[i,j] = total over k,l
    float tot = sm[0] + sm[1] + sm[2] + sm[3] + sm[4] + sm[5] + sm[6] + sm[7];
    tot += __shfl_xor(tot, 8); tot += __shfl_xor(tot, 16);
    if (kq == 0 && lq == 0)
        ws[R2OFF + 0 * R2SZ + nd * 1024 + i * 32 + j] = tot;

    // r123[j,k,l] = sum_i: pair-reduce i within wave, then LDS fp-atomic over waves
    #pragma unroll
    for (int m = 0; m < 8; ++m) {
        float4 w = v[m];
        w.x += __shfl_xor(w.x, 32); w.y += __shfl_xor(w.y, 32);
        w.z += __shfl_xor(w.z, 32); w.w += __shfl_xor(w.w, 32);
        if ((t & 32) == 0) {
            const int kk = kq * 8 + m;
            atomicAdd(&s123[33 * kk + lq * 4 + 0], w.x);
            atomicAdd(&s123[33 * kk + lq * 4 + 1], w.y);
            atomicAdd(&s123[33 * kk + lq * 4 + 2], w.z);
            atomicAdd(&s123[33 * kk + lq * 4 + 3], w.w);
        }
    }
    __syncthreads();

    if (t < 256) {                       // write r123 row + r23 atomics
        const int kk = t >> 3, ll = (t & 7) * 4;
        float4 r;
        r.x = s123[33 * kk + ll + 0];
        r.y = s123[33 * kk + ll + 1];
        r.z = s123[33 * kk + ll + 2];
        r.w = s123[33 * kk + ll + 3];
        *(float4*)(ws + R3OFF + 3 * R3SZ + ((size_t)nd << 15) + ((size_t)j << 10)
                   + kk * 32 + ll) = r;
        float* r23 = ws + R2OFF + 5 * R2SZ + nd * 1024 + kk * 32 + ll;
        unsafeAtomicAdd(r23 + 0, r.x);
        unsafeAtomicAdd(r23 + 1, r.y);
        unsafeAtomicAdd(r23 + 2, r.z);
        unsafeAtomicAdd(r23 + 3, r.w);
    } else if (t < 288) {                // r13[j,l] + r3[l]
        const int l = t - 256;
        float s = 0.f;
        #pragma unroll
        for (int kk = 0; kk < 32; ++kk) s += s123[33 * kk + l];
        ws[R2OFF + 4 * R2SZ + nd * 1024 + j * 32 + l] = s;
        unsafeAtomicAdd(ws + R1OFF + 3 * R1SZ + nd * 32 + l, s);
        s123[1056 + l] = s;
    } else if (t < 320) {                // r12[j,k] + r2[k]
        const int kk = t - 288;
        float s = 0.f;
        #pragma unroll
        for (int l = 0; l < 32; ++l) s += s123[33 * kk + l];
        ws[R2OFF + 3 * R2SZ + nd * 1024 + j * 32 + kk] = s;
        unsafeAtomicAdd(ws + R1OFF + 2 * R1SZ + nd * 32 + kk, s);
    }
    __syncthreads();
    if (t == 0) {                        // r1[j]
        float s = 0.f;
        #pragma unroll
        for (int l = 0; l < 32; ++l) s += s123[1056 + l];
        ws[R1OFF + 1 * R1SZ + nd * 32 + j] = s;
    }
}

// ---------------- K3: T2f/T1f = channel-mixed red2/red1 ----------------
__global__ __launch_bounds__(256) void k_mix21(const float* __restrict__ coefs,
                                               float* __restrict__ ws) {
    __shared__ float cs[4416];
    for (int idx = threadIdx.x; idx < 4416; idx += 256) cs[idx] = coefs[idx];
    __syncthreads();
    const int gid = blockIdx.x * 256 + threadIdx.x;
    if (gid < 98304) {
        const int b2 = gid >> 14;
        const int r  = gid & 16383;
        const int n  = r >> 13;
        const int so = (r >> 10) & 7;
        const int pq = r & 1023;
        float s = 0.f;
        #pragma unroll
        for (int a2 = 0; a2 < 6; ++a2) {
            const float* src = ws + R2OFF + (size_t)a2 * R2SZ + (size_t)(n * 8) * 1024 + pq;
            #pragma unroll
            for (int d = 0; d < 8; ++d)
                s += cs[(d * 8 + so) * 69 + 16 + a2 * 6 + b2] * src[d * 1024];
        }
        ws[T2OFF + (size_t)b2 * R2SZ + (size_t)(n * 8 + so) * 1024 + pq] = s;
    } else if (gid < 100352) {
        const int e  = gid - 98304;
        const int b1 = e >> 9;
        const int r  = e & 511;
        const int n  = r >> 8;
        const int so = (r >> 5) & 7;
        const int p  = r & 31;
        float s = 0.f;
        #pragma unroll
        for (int a1 = 0; a1 < 4; ++a1) {
            const float* src = ws + R1OFF + (size_t)a1 * R1SZ + (size_t)(n * 8) * 32 + p;
            #pragma unroll
            for (int d = 0; d < 8; ++d)
                s += cs[(d * 8 + so) * 69 + a1 * 4 + b1] * src[d * 32];
        }
        ws[T1OFF + (size_t)b1 * R1SZ + (size_t)(n * 8 + so) * 32 + p] = s;
    }
}

// ---------------- K4: U3[b] = mixed red3 + folded T2f/T1f/bias ----------------
__global__ __launch_bounds__(256) void k_mix3(const float* __restrict__ coefs,
                                              const float* __restrict__ bias,
                                              float* __restrict__ ws) {
    __shared__ float cs[4416];
    for (int idx = threadIdx.x; idx < 4416; idx += 256) cs[idx] = coefs[idx];
    __syncthreads();
    const int blk = blockIdx.x;           // 512 = n(1) | soh(1) | cb(7)
    const int cb  = blk & 127;
    const int soh = (blk >> 7) & 1;
    const int n   = blk >> 8;
    const int c   = cb * 256 + threadIdx.x;
    const int p1 = c >> 10, p2 = (c >> 5) & 31, p3 = c & 31;
    float v[4][8];
    #pragma unroll
    for (int a = 0; a < 4; ++a)
        #pragma unroll
        for (int d = 0; d < 8; ++d)
            v[a][d] = ws[R3OFF + (size_t)a * R3SZ + (size_t)(n * 8 + d) * 32768 + c];
    const float* T2 = ws + T2OFF;
    const float* T1 = ws + T1OFF;
    #pragma unroll
    for (int b = 0; b < 4; ++b) {
        #pragma unroll
        for (int so2 = 0; so2 < 4; ++so2) {
            const int so = soh * 4 + so2;
            float s = 0.f;
            #pragma unroll
            for (int a = 0; a < 4; ++a)
                #pragma unroll
                for (int d = 0; d < 8; ++d)
                    s += cs[(d * 8 + so) * 69 + 52 + a * 4 + b] * v[a][d];
            const size_t nso = (size_t)(n * 8 + so);
            if (b == 0) {
                s += T2[0 * R2SZ + nso * 1024 + p1 * 32 + p2];
                s += T2[1 * R2SZ + nso * 1024 + p1 * 32 + p3];
                s += T2[3 * R2SZ + nso * 1024 + p2 * 32 + p3];
                s += T1[0 * R1SZ + nso * 32 + p1];
                s += T1[1 * R1SZ + nso * 32 + p2];
                s += T1[2 * R1SZ + nso * 32 + p3];
                s += bias[so];
            } else if (b == 1) {
                s += T2[2 * R2SZ + nso * 1024 + p1 * 32 + p3];
                s += T2[4 * R2SZ + nso * 1024 + p2 * 32 + p3];
                s += T1[3 * R1SZ + nso * 32 + p3];
            } else if (b == 2) {
                s += T2[5 * R2SZ + nso * 1024 + p2 * 32 + p3];
            }
            ws[U3OFF + (size_t)b * R3SZ + nso * 32768 + c] = s;
        }
    }
}

// ---------------- K5: final broadcast-add + s=4 channel mix ----------------
__global__ __launch_bounds__(256) void k_final(const float* __restrict__ x,
                                               const float* __restrict__ coefs,
                                               const float* __restrict__ ws,
                                               float* __restrict__ out) {
    __shared__ float c68[64];
    if (threadIdx.x < 64) c68[threadIdx.x] = coefs[threadIdx.x * 69 + 68];
    __syncthreads();
    const int b = blockIdx.x;           // (n*32+i)*32 + j
    const int j = b & 31;
    const int i = (b >> 5) & 31;
    const int n = b >> 10;
    const int t = threadIdx.x;
    const int k = t >> 3, lq = t & 7;

    float4 xv[8];
    const float* xb = x + ((size_t)n << 23) + ((size_t)i << 15) + j * 1024 + k * 32 + lq * 4;
    #pragma unroll
    for (int d = 0; d < 8; ++d) xv[d] = *(const float4*)(xb + ((size_t)d << 20));

    const float* U = ws + U3OFF;
    const size_t c012 = (size_t)i * 1024 + j * 32 + k;
    const size_t c013 = (size_t)i * 1024 + j * 32 + lq * 4;
    const size_t c023 = (size_t)i * 1024 + k * 32 + lq * 4;
    const size_t c123 = (size_t)j * 1024 + k * 32 + lq * 4;

    #pragma unroll
    for (int so = 0; so < 8; ++so) {
        const size_t nso = (size_t)(n * 8 + so) << 15;
        const float  u0 = U[0 * R3SZ + nso + c012];
        const float4 u1 = *(const float4*)(U + 1 * R3SZ + nso + c013);
        const float4 u2 = *(const float4*)(U + 2 * R3SZ + nso + c023);
        const float4 u3 = *(const float4*)(U + 3 * R3SZ + nso + c123);
        float4 acc;
        acc.x = u0 + u1.x + u2.x + u3.x;
        acc.y = u0 + u1.y + u2.y + u3.y;
        acc.z = u0 + u1.z + u2.z + u3.z;
        acc.w = u0 + u1.w + u2.w + u3.w;
        #pragma unroll
        for (int d = 0; d < 8; ++d) {
            const float w = c68[d * 8 + so];
            acc.x += w * xv[d].x; acc.y += w * xv[d].y;
            acc.z += w * xv[d].z; acc.w += w * xv[d].w;
        }
        *(float4*)(out + ((size_t)(n * 8 + so) << 20) + ((size_t)i << 15)
                   + j * 1024 + k * 32 + lq * 4) = acc;
    }
}

extern "C" void kernel_launch(void* const* d_in, const int* in_sizes, int n_in,
                              void* d_out, int out_size, void* d_ws, size_t ws_size,
                              hipStream_t stream) {
    const float* x     = (const float*)d_in[0];
    const float* coefs = (const float*)d_in[1];
    const float* bias  = (const float*)d_in[2];
    float* out = (float*)d_out;
    float* ws  = (float*)d_ws;

    // zero atomic targets: r23 (red2 b2=5) and r2,r3 (red1 b1=2,3)
    hipMemsetAsync(ws + R2OFF + 5 * R2SZ, 0, R2SZ * sizeof(float), stream);
    hipMemsetAsync(ws + R1OFF + 2 * R1SZ, 0, 2 * R1SZ * sizeof(float), stream);

    hipLaunchKernelGGL(k_r023,  dim3(512),  dim3(1024), 0, stream, x, ws);
    hipLaunchKernelGGL(k_rowj,  dim3(512),  dim3(1024), 0, stream, x, ws);
    hipLaunchKernelGGL(k_mix21, dim3(392),  dim3(256),  0, stream, coefs, ws);
    hipLaunchKernelGGL(k_mix3,  dim3(512),  dim3(256),  0, stream, coefs, bias, ws);
    hipLaunchKernelGGL(k_final, dim3(2048), dim3(256),  0, stream, x, coefs, ws, out);
}

// Round 3
// 203.437 us; speedup vs baseline: 1.0601x; 1.0133x over previous
//
#include <hip/hip_runtime.h>

// SetEq4to4: out[n,so,i,j,k,l] = sum over 69 basis ops (A,B) + bias.
// n=2, d=8, so=8, N=32, basis=69.
//
// Pipeline (all kernels atomic-free, short dependency chains):
//   KA k_plane (block per (nd,i,jq)): x -> r012[i,j,k], r013[i,j,l]
//   KB k_col   (block per (nd,i) | (nd,j)): x -> r023[i,k,l], r123[j,k,l]
//   K3 k_red21: red2 (6) + red1 (4) derived from r012/r013/r023
//   K4 k_mix21: T2f/T1f = channel-mixed red2/red1
//   K5 k_mix3:  U3[b] = channel-mixed red3 + folded T2f/T1f/bias
//   K6 k_final: out = sum_d c68*x + U012 + U013 + U023 + U123

constexpr size_t R3SZ  = 524288;   // per-a: 16 nd * 32768
constexpr size_t R2SZ  = 16384;    // per-b2: 16 nd * 1024
constexpr size_t R1SZ  = 512;      // per-b1: 16 nd * 32
constexpr size_t R3OFF = 0;
constexpr size_t R2OFF = R3OFF + 4 * R3SZ;   // red2: b2 0..5 = (01)(02)(03)(12)(13)(23)
constexpr size_t R1OFF = R2OFF + 6 * R2SZ;   // red1: b1 0..3 = (0)(1)(2)(3)
constexpr size_t T2OFF = R1OFF + 4 * R1SZ;
constexpr size_t T1OFF = T2OFF + 6 * R2SZ;
constexpr size_t U3OFF = T1OFF + 4 * R1SZ;
// total ws floats: U3OFF + 4*R3SZ = 4395008  (~17.6 MiB)

// ---------------- KA: r012[i,j,k] + r013[i,j,l]. block = (nd, i, jq) ----------------
__global__ __launch_bounds__(256) void k_plane(const float* __restrict__ x,
                                               float* __restrict__ ws) {
    __shared__ float4 cp[4][8];
    __shared__ float b012[256];
    __shared__ float b013[256];
    const int bid = blockIdx.x;         // 2048 = nd(4b) | i(5b) | jq(2b)
    const int jq = bid & 3;
    const int i  = (bid >> 2) & 31;
    const int nd = bid >> 7;
    const int t  = threadIdx.x;
    const int w  = t >> 6;
    const int lane = t & 63;
    const float* xp = x + ((size_t)nd << 20) + ((size_t)i << 15) + (size_t)jq * 8192;

    #pragma unroll
    for (int jj = 0; jj < 8; ++jj) {
        float4 v = *(const float4*)(xp + jj * 1024 + t * 4);   // k=t>>3, l=(t&7)*4
        // r012[k] = row sum over l: hsum + butterfly over lane bits 0..2
        float h = v.x + v.y + v.z + v.w;
        h += __shfl_xor(h, 1); h += __shfl_xor(h, 2); h += __shfl_xor(h, 4);
        if ((t & 7) == 0) b012[jj * 32 + (t >> 3)] = h;
        // col partials over this wave's 8 k's: butterfly over lane bits 3..5
        v.x += __shfl_xor(v.x, 8);  v.y += __shfl_xor(v.y, 8);
        v.z += __shfl_xor(v.z, 8);  v.w += __shfl_xor(v.w, 8);
        v.x += __shfl_xor(v.x, 16); v.y += __shfl_xor(v.y, 16);
        v.z += __shfl_xor(v.z, 16); v.w += __shfl_xor(v.w, 16);
        v.x += __shfl_xor(v.x, 32); v.y += __shfl_xor(v.y, 32);
        v.z += __shfl_xor(v.z, 32); v.w += __shfl_xor(v.w, 32);
        if (lane < 8) cp[w][lane] = v;
        __syncthreads();
        if (t < 8) {
            float4 s0 = cp[0][t], s1 = cp[1][t], s2 = cp[2][t], s3 = cp[3][t];
            float4 s;
            s.x = s0.x + s1.x + s2.x + s3.x;
            s.y = s0.y + s1.y + s2.y + s3.y;
            s.z = s0.z + s1.z + s2.z + s3.z;
            s.w = s0.w + s1.w + s2.w + s3.w;
            *(float4*)(&b013[jj * 32 + t * 4]) = s;            // l = t*4..t*4+3
        }
        __syncthreads();
    }
    const size_t base = ((size_t)nd << 15) + ((size_t)i << 10) + jq * 256;
    ws[R3OFF + base + t]         = b012[t];                    // [i,j,k]
    ws[R3OFF + R3SZ + base + t]  = b013[t];                    // [i,j,l]
}

// ---------------- KB: r023[i,k,l] (b<512) and r123[j,k,l] (b>=512) ----------------
__global__ __launch_bounds__(256) void k_col(const float* __restrict__ x,
                                             float* __restrict__ ws) {
    const int b = blockIdx.x;           // 1024
    const int t = threadIdx.x;          // t*4 = k*32 + lq*4
    if (b < 512) {
        const int i  = b & 31;
        const int nd = b >> 5;
        const float* xp = x + ((size_t)nd << 20) + ((size_t)i << 15) + t * 4;
        float4 acc = {0.f, 0.f, 0.f, 0.f};
        #pragma unroll 8
        for (int j = 0; j < 32; ++j) {
            float4 v = *(const float4*)(xp + j * 1024);
            acc.x += v.x; acc.y += v.y; acc.z += v.z; acc.w += v.w;
        }
        *(float4*)(ws + R3OFF + 2 * R3SZ + ((size_t)nd << 15) + ((size_t)i << 10)
                   + t * 4) = acc;
    } else {
        const int bb = b - 512;
        const int j  = bb & 31;
        const int nd = bb >> 5;
        const float* xp = x + ((size_t)nd << 20) + (size_t)j * 1024 + t * 4;
        float4 acc = {0.f, 0.f, 0.f, 0.f};
        #pragma unroll 8
        for (int i = 0; i < 32; ++i) {
            float4 v = *(const float4*)(xp + ((size_t)i << 15));
            acc.x += v.x; acc.y += v.y; acc.z += v.z; acc.w += v.w;
        }
        *(float4*)(ws + R3OFF + 3 * R3SZ + ((size_t)nd << 15) + ((size_t)j << 10)
                   + t * 4) = acc;
    }
}

// ---------------- K3: red2 (6) + red1 (4) from red3 ----------------
__global__ __launch_bounds__(256) void k_red21(float* __restrict__ ws) {
    const int gid = blockIdx.x * 256 + threadIdx.x;   // grid 392*256 = 100352
    if (gid < 98304) {
        const int b2 = gid >> 14;
        const int r  = gid & 16383;
        const int nd = r >> 10;
        const int p = (r >> 5) & 31, q = r & 31;
        const float* r012 = ws + R3OFF + ((size_t)nd << 15);
        const float* r013 = r012 + R3SZ;
        const float* r023 = r012 + 2 * R3SZ;
        float s = 0.f;
        switch (b2) {
            case 0: { const float* s0 = r012 + p * 1024 + q * 32;
                      for (int m = 0; m < 32; ++m) s += s0[m]; } break;
            case 1: { const float* s0 = r012 + p * 1024 + q;
                      for (int m = 0; m < 32; ++m) s += s0[m * 32]; } break;
            case 2: { const float* s0 = r013 + p * 1024 + q;
                      for (int m = 0; m < 32; ++m) s += s0[m * 32]; } break;
            case 3: { const float* s0 = r012 + p * 32 + q;
                      for (int m = 0; m < 32; ++m) s += s0[m * 1024]; } break;
            case 4: { const float* s0 = r013 + p * 32 + q;
                      for (int m = 0; m < 32; ++m) s += s0[m * 1024]; } break;
            default:{ const float* s0 = r023 + p * 32 + q;
                      for (int m = 0; m < 32; ++m) s += s0[m * 1024]; } break;
        }
        ws[R2OFF + (size_t)b2 * R2SZ + (size_t)nd * 1024 + p * 32 + q] = s;
    } else if (gid < 100352) {
        const int e  = gid - 98304;
        const int b1 = e >> 9;
        const int r  = e & 511;
        const int nd = r >> 5, p = r & 31;
        const float* r012 = ws + R3OFF + ((size_t)nd << 15);
        const float* r013 = r012 + R3SZ;
        float s = 0.f;
        if (b1 == 0)      { const float* s0 = r012 + p * 1024;
                            for (int m = 0; m < 1024; ++m) s += s0[m]; }
        else if (b1 == 1) { const float* s0 = r012 + p * 32;
                            for (int a = 0; a < 32; ++a) for (int m = 0; m < 32; ++m)
                                s += s0[a * 1024 + m]; }
        else if (b1 == 2) { const float* s0 = r012 + p;
                            for (int a = 0; a < 32; ++a) for (int m = 0; m < 32; ++m)
                                s += s0[a * 1024 + m * 32]; }
        else              { const float* s0 = r013 + p;
                            for (int a = 0; a < 32; ++a) for (int m = 0; m < 32; ++m)
                                s += s0[a * 1024 + m * 32]; }
        ws[R1OFF + (size_t)b1 * R1SZ + (size_t)nd * 32 + p] = s;
    }
}

// ---------------- K4: T2f/T1f = channel-mixed red2/red1 ----------------
__global__ __launch_bounds__(256) void k_mix21(const float* __restrict__ coefs,
                                               float* __restrict__ ws) {
    __shared__ float cs[4416];
    for (int idx = threadIdx.x; idx < 4416; idx += 256) cs[idx] = coefs[idx];
    __syncthreads();
    const int gid = blockIdx.x * 256 + threadIdx.x;
    if (gid < 98304) {
        const int b2 = gid >> 14;
        const int r  = gid & 16383;
        const int n  = r >> 13;
        const int so = (r >> 10) & 7;
        const int pq = r & 1023;
        float s = 0.f;
        #pragma unroll
        for (int a2 = 0; a2 < 6; ++a2) {
            const float* src = ws + R2OFF + (size_t)a2 * R2SZ + (size_t)(n * 8) * 1024 + pq;
            #pragma unroll
            for (int d = 0; d < 8; ++d)
                s += cs[(d * 8 + so) * 69 + 16 + a2 * 6 + b2] * src[d * 1024];
        }
        ws[T2OFF + (size_t)b2 * R2SZ + (size_t)(n * 8 + so) * 1024 + pq] = s;
    } else if (gid < 100352) {
        const int e  = gid - 98304;
        const int b1 = e >> 9;
        const int r  = e & 511;
        const int n  = r >> 8;
        const int so = (r >> 5) & 7;
        const int p  = r & 31;
        float s = 0.f;
        #pragma unroll
        for (int a1 = 0; a1 < 4; ++a1) {
            const float* src = ws + R1OFF + (size_t)a1 * R1SZ + (size_t)(n * 8) * 32 + p;
            #pragma unroll
            for (int d = 0; d < 8; ++d)
                s += cs[(d * 8 + so) * 69 + a1 * 4 + b1] * src[d * 32];
        }
        ws[T1OFF + (size_t)b1 * R1SZ + (size_t)(n * 8 + so) * 32 + p] = s;
    }
}

// ---------------- K5: U3[b] = mixed red3 + folded T2f/T1f/bias ----------------
__global__ __launch_bounds__(256) void k_mix3(const float* __restrict__ coefs,
                                              const float* __restrict__ bias,
                                              float* __restrict__ ws) {
    __shared__ float cs[4416];
    for (int idx = threadIdx.x; idx < 4416; idx += 256) cs[idx] = coefs[idx];
    __syncthreads();
    const int blk = blockIdx.x;           // 512 = n(1) | soh(1) | cb(7)
    const int cb  = blk & 127;
    const int soh = (blk >> 7) & 1;
    const int n   = blk >> 8;
    const int c   = cb * 256 + threadIdx.x;
    const int p1 = c >> 10, p2 = (c >> 5) & 31, p3 = c & 31;
    float v[4][8];
    #pragma unroll
    for (int a = 0; a < 4; ++a)
        #pragma unroll
        for (int d = 0; d < 8; ++d)
            v[a][d] = ws[R3OFF + (size_t)a * R3SZ + (size_t)(n * 8 + d) * 32768 + c];
    const float* T2 = ws + T2OFF;
    const float* T1 = ws + T1OFF;
    #pragma unroll
    for (int b = 0; b < 4; ++b) {
        #pragma unroll
        for (int so2 = 0; so2 < 4; ++so2) {
            const int so = soh * 4 + so2;
            float s = 0.f;
            #pragma unroll
            for (int a = 0; a < 4; ++a)
                #pragma unroll
                for (int d = 0; d < 8; ++d)
                    s += cs[(d * 8 + so) * 69 + 52 + a * 4 + b] * v[a][d];
            const size_t nso = (size_t)(n * 8 + so);
            if (b == 0) {
                s += T2[0 * R2SZ + nso * 1024 + p1 * 32 + p2];
                s += T2[1 * R2SZ + nso * 1024 + p1 * 32 + p3];
                s += T2[3 * R2SZ + nso * 1024 + p2 * 32 + p3];
                s += T1[0 * R1SZ + nso * 32 + p1];
                s += T1[1 * R1SZ + nso * 32 + p2];
                s += T1[2 * R1SZ + nso * 32 + p3];
                s += bias[so];
            } else if (b == 1) {
                s += T2[2 * R2SZ + nso * 1024 + p1 * 32 + p3];
                s += T2[4 * R2SZ + nso * 1024 + p2 * 32 + p3];
                s += T1[3 * R1SZ + nso * 32 + p3];
            } else if (b == 2) {
                s += T2[5 * R2SZ + nso * 1024 + p2 * 32 + p3];
            }
            ws[U3OFF + (size_t)b * R3SZ + nso * 32768 + c] = s;
        }
    }
}

// ---------------- K6: final broadcast-add + s=4 channel mix ----------------
__global__ __launch_bounds__(256) void k_final(const float* __restrict__ x,
                                               const float* __restrict__ coefs,
                                               const float* __restrict__ ws,
                                               float* __restrict__ out) {
    __shared__ float c68[64];
    if (threadIdx.x < 64) c68[threadIdx.x] = coefs[threadIdx.x * 69 + 68];
    __syncthreads();
    const int b = blockIdx.x;           // (n*32+i)*32 + j
    const int j = b & 31;
    const int i = (b >> 5) & 31;
    const int n = b >> 10;
    const int t = threadIdx.x;
    const int k = t >> 3, lq = t & 7;

    float4 xv[8];
    const float* xb = x + ((size_t)n << 23) + ((size_t)i << 15) + j * 1024 + k * 32 + lq * 4;
    #pragma unroll
    for (int d = 0; d < 8; ++d) xv[d] = *(const float4*)(xb + ((size_t)d << 20));

    const float* U = ws + U3OFF;
    const size_t c012 = (size_t)i * 1024 + j * 32 + k;
    const size_t c013 = (size_t)i * 1024 + j * 32 + lq * 4;
    const size_t c023 = (size_t)i * 1024 + k * 32 + lq * 4;
    const size_t c123 = (size_t)j * 1024 + k * 32 + lq * 4;

    #pragma unroll
    for (int so = 0; so < 8; ++so) {
        const size_t nso = (size_t)(n * 8 + so) << 15;
        const float  u0 = U[0 * R3SZ + nso + c012];
        const float4 u1 = *(const float4*)(U + 1 * R3SZ + nso + c013);
        const float4 u2 = *(const float4*)(U + 2 * R3SZ + nso + c023);
        const float4 u3 = *(const float4*)(U + 3 * R3SZ + nso + c123);
        float4 acc;
        acc.x = u0 + u1.x + u2.x + u3.x;
        acc.y = u0 + u1.y + u2.y + u3.y;
        acc.z = u0 + u1.z + u2.z + u3.z;
        acc.w = u0 + u1.w + u2.w + u3.w;
        #pragma unroll
        for (int d = 0; d < 8; ++d) {
            const float w = c68[d * 8 + so];
            acc.x += w * xv[d].x; acc.y += w * xv[d].y;
            acc.z += w * xv[d].z; acc.w += w * xv[d].w;
        }
        *(float4*)(out + ((size_t)(n * 8 + so) << 20) + ((size_t)i << 15)
                   + j * 1024 + k * 32 + lq * 4) = acc;
    }
}

extern "C" void kernel_launch(void* const* d_in, const int* in_sizes, int n_in,
                              void* d_out, int out_size, void* d_ws, size_t ws_size,
                              hipStream_t stream) {
    const float* x     = (const float*)d_in[0];
    const float* coefs = (const float*)d_in[1];
    const float* bias  = (const float*)d_in[2];
    float* out = (float*)d_out;
    float* ws  = (float*)d_ws;

    hipLaunchKernelGGL(k_plane, dim3(2048), dim3(256), 0, stream, x, ws);
    hipLaunchKernelGGL(k_col,   dim3(1024), dim3(256), 0, stream, x, ws);
    hipLaunchKernelGGL(k_red21, dim3(392),  dim3(256), 0, stream, ws);
    hipLaunchKernelGGL(k_mix21, dim3(392),  dim3(256), 0, stream, coefs, ws);
    hipLaunchKernelGGL(k_mix3,  dim3(512),  dim3(256), 0, stream, coefs, bias, ws);
    hipLaunchKernelGGL(k_final, dim3(2048), dim3(256), 0, stream, x, coefs, ws, out);
}